// Round 11
// baseline (218.235 us; speedup 1.0000x reference)
//
#include <hip/hip_runtime.h>
#include <hip/hip_bf16.h>

typedef __hip_bfloat16 bf16;
typedef short short8 __attribute__((ext_vector_type(8)));
typedef short bs4 __attribute__((ext_vector_type(4)));   // NOT short4 (HIP owns that name)
typedef float f32x4 __attribute__((ext_vector_type(4)));
typedef float f32x16 __attribute__((ext_vector_type(16)));

#define MFMA_BF16(a, b, c) __builtin_amdgcn_mfma_f32_16x16x32_bf16(a, b, c, 0, 0, 0)
#define MFMA32_BF16(a, b, c) __builtin_amdgcn_mfma_f32_32x32x16_bf16(a, b, c, 0, 0, 0)

// log2(e)/sqrt(1024): folded into Q-projection so attn exp is raw v_exp_f32
#define QSCALE 0.045084439f

// async global->LDS 16B: LDS dest is wave-uniform base; HW scatters lane i to +16B*i
__device__ __forceinline__ void async_copy16(const bf16* g, bf16* l) {
    __builtin_amdgcn_global_load_lds(
        (const __attribute__((address_space(1))) unsigned int*)(const void*)g,
        (__attribute__((address_space(3))) unsigned int*)(void*)l, 16, 0, 0);
}

// ---------------------------------------------------------------------------
// f32 -> bf16 pre-convert: q,k,v (4M elems each), Wq,Wk,Wv,Wo (1M each).
// ---------------------------------------------------------------------------
__global__ __launch_bounds__(256) void convert_all(
    const float* __restrict__ q, const float* __restrict__ k, const float* __restrict__ v,
    const float* __restrict__ wq, const float* __restrict__ wk,
    const float* __restrict__ wv, const float* __restrict__ wo,
    bf16* __restrict__ qb, bf16* __restrict__ kb, bf16* __restrict__ vb,
    bf16* __restrict__ wqb, bf16* __restrict__ wkb, bf16* __restrict__ wvb,
    bf16* __restrict__ wob)
{
    int blk = blockIdx.x;
    const float* s; bf16* d; int rel;
    if      (blk < 1024) { s = q;  d = qb;  rel = blk; }
    else if (blk < 2048) { s = k;  d = kb;  rel = blk - 1024; }
    else if (blk < 3072) { s = v;  d = vb;  rel = blk - 2048; }
    else if (blk < 3328) { s = wq; d = wqb; rel = blk - 3072; }
    else if (blk < 3584) { s = wk; d = wkb; rel = blk - 3328; }
    else if (blk < 3840) { s = wv; d = wvb; rel = blk - 3584; }
    else                 { s = wo; d = wob; rel = blk - 3840; }
    size_t base = (size_t)rel * 1024 + threadIdx.x;  // float4 index
#pragma unroll
    for (int i = 0; i < 4; i++) {
        float4 f = ((const float4*)s)[base + i * 256];
        union { bf16 h[4]; uint2 u; } pk;
        pk.h[0] = (bf16)f.x; pk.h[1] = (bf16)f.y;
        pk.h[2] = (bf16)f.z; pk.h[3] = (bf16)f.w;
        ((uint2*)d)[base + i * 256] = pk.u;
    }
}

// ---------------------------------------------------------------------------
// Fused QKV projection: grid (x = m-block [32], y = n-block + 8*sel [24]).
// XCD swizzle: blocks sharing the A-row-tile (fixed x, all y) have
// id = x + 32*y -> id%8 == x%8 -> same XCD -> A fetched once per XCD.
// 128x128 tile, BK=64, global_load_lds staging, XOR chunk swizzle.
// R9 single-barrier T3 loop (kept: net positive for the GEMMs).
// sel 0: Q (scaled by QSCALE); sel 1: K; sel 2: V transposed [b][h][64][2048].
// ---------------------------------------------------------------------------
__global__ __launch_bounds__(256) void gemm_qkv(
    const bf16* __restrict__ qb, const bf16* __restrict__ kb, const bf16* __restrict__ vb,
    const bf16* __restrict__ wqb, const bf16* __restrict__ wkb, const bf16* __restrict__ wvb,
    const float* __restrict__ bq, const float* __restrict__ bk, const float* __restrict__ bv,
    bf16* __restrict__ Qp, bf16* __restrict__ Kp, bf16* __restrict__ Vt)
{
    __shared__ bf16 Al[2][128 * 64];   // 2 x 16 KB
    __shared__ bf16 Bl[2][128 * 64];   // 2 x 16 KB

    const int sel = blockIdx.y >> 3;
    const bf16* A; const bf16* W; const float* bias;
    if      (sel == 0) { A = qb; W = wqb; bias = bq; }
    else if (sel == 1) { A = kb; W = wkb; bias = bk; }
    else               { A = vb; W = wvb; bias = bv; }

    const int K = 1024, N = 1024;
    const int t = threadIdx.x;
    const int lane = t & 63, wave = t >> 6;
    const int ln = lane & 15, quad = lane >> 4;
    const int wm = wave >> 1, wn = wave & 1;
    const int m0 = blockIdx.x * 128, n0 = (blockIdx.y & 7) * 128;

    f32x4 acc[4][4];
#pragma unroll
    for (int i = 0; i < 4; i++)
#pragma unroll
        for (int j = 0; j < 4; j++) acc[i][j] = (f32x4){0.f, 0.f, 0.f, 0.f};

    const int lk = ln & 7;
    const int srow = t >> 3, sidx0 = t & 7;

#define STAGE_AB(buf_, k0_) do {                                               \
    const bf16* Ab = A + (size_t)m0 * K + (k0_);                               \
    const bf16* Wb = W + (size_t)n0 * K + (k0_);                               \
    _Pragma("unroll")                                                          \
    for (int p = 0; p < 4; p++) {                                              \
        int row = p * 32 + srow, idx = sidx0 ^ (row & 7);                      \
        async_copy16(Ab + (size_t)row * K + idx * 8,                           \
                     &Al[buf_][(p * 256 + wave * 64) * 8]);                    \
    }                                                                          \
    _Pragma("unroll")                                                          \
    for (int p = 0; p < 4; p++) {                                              \
        int row = p * 32 + srow, idx = sidx0 ^ (row & 7);                      \
        async_copy16(Wb + (size_t)row * K + idx * 8,                           \
                     &Bl[buf_][(p * 256 + wave * 64) * 8]);                    \
    }                                                                          \
} while (0)

    STAGE_AB(0, 0);                                  // prologue
    asm volatile("s_waitcnt vmcnt(0)" ::: "memory");
    __builtin_amdgcn_s_barrier();

    for (int k0 = 0; k0 < K; k0 += 64) {
        const int cur = (k0 >> 6) & 1;
        if (k0 < K - 64)
            STAGE_AB(cur ^ 1, k0 + 64);              // overlaps this compute

        const bf16* Alc = Al[cur];
        const bf16* Blc = Bl[cur];

#pragma unroll
        for (int kk = 0; kk < 2; kk++) {
            short8 af[4], bfr[4];
#pragma unroll
            for (int i = 0; i < 4; i++) {
                int r = wm * 64 + i * 16 + ln;
                af[i] = *(const short8*)&Alc[r * 64 + (((kk << 2) | quad) ^ lk) * 8];
            }
#pragma unroll
            for (int j = 0; j < 4; j++) {
                int r = wn * 64 + j * 16 + ln;
                bfr[j] = *(const short8*)&Blc[r * 64 + (((kk << 2) | quad) ^ lk) * 8];
            }
            __builtin_amdgcn_s_setprio(1);
#pragma unroll
            for (int i = 0; i < 4; i++)
#pragma unroll
                for (int j = 0; j < 4; j++)
                    acc[i][j] = MFMA_BF16(af[i], bfr[j], acc[i][j]);
            __builtin_amdgcn_s_setprio(0);
        }

        asm volatile("s_waitcnt vmcnt(0)" ::: "memory"); // next buf staged
        __builtin_amdgcn_s_barrier();                    // all reads+loads done
    }
#undef STAGE_AB

    // epilogue: col(n) = ln, row(m) = quad*4 + r
#pragma unroll
    for (int j = 0; j < 4; j++) {
        int c = n0 + wn * 64 + j * 16 + ln;
        float bv2 = bias[c];
        if (sel == 2) {
            int h = c >> 6, dd = c & 63;
#pragma unroll
            for (int i = 0; i < 4; i++) {
                int m = m0 + wm * 64 + i * 16 + quad * 4;
                int bb = m >> 11, s = m & 2047;
                union { bf16 h4[4]; uint2 u; } pk;
#pragma unroll
                for (int r = 0; r < 4; r++) pk.h4[r] = (bf16)(acc[i][j][r] + bv2);
                *(uint2*)&Vt[(((size_t)(bb * 16 + h)) * 64 + dd) * 2048 + s] = pk.u;
            }
        } else {
            bf16* out = (sel == 0) ? Qp : Kp;
            float scl = (sel == 0) ? QSCALE : 1.0f;
#pragma unroll
            for (int i = 0; i < 4; i++) {
                int rb = m0 + wm * 64 + i * 16 + quad * 4;
#pragma unroll
                for (int r = 0; r < 4; r++)
                    out[(size_t)(rb + r) * N + c] = (bf16)((acc[i][j][r] + bv2) * scl);
            }
        }
    }
}

// ---------------------------------------------------------------------------
// Final GEMM: out = AO * Wo^T + bo, f32 output. 128(M)x64(N) tile, dbuf,
// single-barrier T3 loop, grid (32,16). (R9 form, kept.)
// ---------------------------------------------------------------------------
__global__ __launch_bounds__(256) void gemm_fin(
    const bf16* __restrict__ A, const bf16* __restrict__ W,
    const float* __restrict__ bias, float* __restrict__ C)
{
    __shared__ bf16 Al[2][128 * 64];   // 32 KB
    __shared__ bf16 Bl[2][64 * 64];    // 16 KB

    const int K = 1024, N = 1024;
    const int t = threadIdx.x;
    const int lane = t & 63, wave = t >> 6;
    const int ln = lane & 15, quad = lane >> 4;
    const int wm = wave >> 1, wn = wave & 1;
    const int m0 = blockIdx.x * 128, n0 = blockIdx.y * 64;

    f32x4 acc[4][2];
#pragma unroll
    for (int i = 0; i < 4; i++)
#pragma unroll
        for (int j = 0; j < 2; j++) acc[i][j] = (f32x4){0.f, 0.f, 0.f, 0.f};

    const int lk = ln & 7;
    const int srow = t >> 3, sidx0 = t & 7;

#define STAGE_AB(buf_, k0_) do {                                               \
    const bf16* Ab = A + (size_t)m0 * K + (k0_);                               \
    const bf16* Wb = W + (size_t)n0 * K + (k0_);                               \
    _Pragma("unroll")                                                          \
    for (int p = 0; p < 4; p++) {                                              \
        int row = p * 32 + srow, idx = sidx0 ^ (row & 7);                      \
        async_copy16(Ab + (size_t)row * K + idx * 8,                           \
                     &Al[buf_][(p * 256 + wave * 64) * 8]);                    \
    }                                                                          \
    _Pragma("unroll")                                                          \
    for (int p = 0; p < 2; p++) {                                              \
        int row = p * 32 + srow, idx = sidx0 ^ (row & 7);                      \
        async_copy16(Wb + (size_t)row * K + idx * 8,                           \
                     &Bl[buf_][(p * 256 + wave * 64) * 8]);                    \
    }                                                                          \
} while (0)

    STAGE_AB(0, 0);                                  // prologue
    asm volatile("s_waitcnt vmcnt(0)" ::: "memory");
    __builtin_amdgcn_s_barrier();

    for (int k0 = 0; k0 < K; k0 += 64) {
        const int cur = (k0 >> 6) & 1;
        if (k0 < K - 64)
            STAGE_AB(cur ^ 1, k0 + 64);              // overlaps this compute

        const bf16* Alc = Al[cur];
        const bf16* Blc = Bl[cur];

#pragma unroll
        for (int kk = 0; kk < 2; kk++) {
            short8 af[4], bfr[2];
#pragma unroll
            for (int i = 0; i < 4; i++) {
                int r = wm * 64 + i * 16 + ln;
                af[i] = *(const short8*)&Alc[r * 64 + (((kk << 2) | quad) ^ lk) * 8];
            }
#pragma unroll
            for (int j = 0; j < 2; j++) {
                int r = wn * 32 + j * 16 + ln;
                bfr[j] = *(const short8*)&Blc[r * 64 + (((kk << 2) | quad) ^ lk) * 8];
            }
            __builtin_amdgcn_s_setprio(1);
#pragma unroll
            for (int i = 0; i < 4; i++)
#pragma unroll
                for (int j = 0; j < 2; j++)
                    acc[i][j] = MFMA_BF16(af[i], bfr[j], acc[i][j]);
            __builtin_amdgcn_s_setprio(0);
        }

        asm volatile("s_waitcnt vmcnt(0)" ::: "memory");
        __builtin_amdgcn_s_barrier();
    }
#undef STAGE_AB

#pragma unroll
    for (int j = 0; j < 2; j++) {
        int c = n0 + wn * 32 + j * 16 + ln;
        float bv2 = bias[c];
#pragma unroll
        for (int i = 0; i < 4; i++) {
            int rb = m0 + wm * 64 + i * 16 + quad * 4;
#pragma unroll
            for (int r = 0; r < 4; r++)
                C[(size_t)(rb + r) * N + c] = acc[i][j][r] + bv2;
        }
    }
}

// ---------------------------------------------------------------------------
// Flash attention, 32x32x16 MFMA. Grid (x = h + 16*b [32], y = qt [16]),
// 512 threads / 8 waves; wave = 32 queries (qw) x key-half (keyhalf).
// R10: (a) R8's measured-faster sync shape restored (counted vmcnt(4) at
// top + two barriers); (b) kg software pipeline (T15-style): QK(0) ->
// [K-frags(1) ds_reads overlap] -> exp2(0) -> QK(1) -> ol/PV(0) -> exp2(1)
// (VALU overlaps PV(0) in the matrix pipe) -> ol/PV(1). Breaks the serial
// per-kg chain that left all three pipes at ~40%.
// R7: ones-MFMA denominator (inv lane-local). R6/R8: occupancy is
// register-walled at 4 waves/SIMD; matrix-pipe floor ~17 us.
// ---------------------------------------------------------------------------
__global__ __launch_bounds__(512, 4) void attn128q(
    const bf16* __restrict__ Q, const bf16* __restrict__ K,
    const bf16* __restrict__ V, bf16* __restrict__ O)
{
    const int S = 2048, D = 1024;
    __shared__ bf16 Kl[2][128 * 64];    // 2 x 16 KB [key][d], 16B-chunk ^(row&7)
    __shared__ bf16 Vl[2][64 * 128];    // 2 x 16 KB [d][key], 16B-chunk ^(row&15)

    const int t = threadIdx.x, lane = t & 63, wave = t >> 6;   // wave 0..7
    const int lo = lane & 31, hi = lane >> 5;
    const int keyhalf = wave >> 2;      // 0: keys 0-63 of tile, 1: keys 64-127
    const int qw = wave & 3;            // query group: q0 = qt*128 + qw*32
    const int h = blockIdx.x & 15, b = blockIdx.x >> 4, qt = blockIdx.y;
    const size_t kqbase = (size_t)b * S * D + (size_t)h * 64;
    const size_t vbase = ((size_t)(b * 16 + h)) * 64 * 2048;

    // Q fragments (pre-scaled by QSCALE): lane: row q0+lo, d = s*16 + hi*8
    const int q0 = qt * 128 + qw * 32;
    short8 aq[4];
    {
        const bf16* qp = Q + kqbase + (size_t)(q0 + lo) * D + hi * 8;
#pragma unroll
        for (int s = 0; s < 4; s++) aq[s] = *(const short8*)(qp + s * 16);
    }
    // Force the Q-load vmcnt wait here, before the pipelined loop.
    asm volatile("" :: "v"(aq[0]), "v"(aq[1]), "v"(aq[2]), "v"(aq[3]));

    f32x16 o0, o1, ol;                   // O accum: d = lo (o0), 32+lo (o1);
                                         // ol = P row-sums (denominator)
#pragma unroll
    for (int i = 0; i < 16; i++) { o0[i] = 0.f; o1[i] = 0.f; ol[i] = 0.f; }

    // ones B-frag (bf16 1.0 splat) for the denominator MFMA
    const short8 vones = (short8)(short)0x3F80;

    // K A-frag offsets: row = keyhalf*64 + kg*32 + lo; row&7 == lo&7, so the
    // swizzled chunk (2s+hi)^(lo&7) is kg-invariant. Element offsets:
    int koff[4];
#pragma unroll
    for (int s = 0; s < 4; s++)
        koff[s] = lo * 64 + (((2 * s + hi) ^ (lo & 7)) * 8);
    const int khbase = keyhalf * 64 * 64;       // elements to this wave's keys

    // V B-frag: element off = (db*32+lo)*128 + ((x0 ^ m)*8) + hi*4,
    // m = kg*4 + 2c + g  (bits 0-2; keyhalf*8 is bit 3 -> XOR-combinable)
    const int x0 = (keyhalf * 8) ^ (lo & 15);
    const int vbl = lo * 128 + hi * 4;

    // staging indices (512 threads: 2 K chunks + 2 V chunks per thread)
    const int krow = t >> 3, kidx = t & 7;        // K: 8 chunks/row
    const int vrow = t >> 4, vidx = t & 15;       // V: 16 chunks/row

#define STAGE_KV(buf_, kt_) do {                                               \
    _Pragma("unroll")                                                          \
    for (int p = 0; p < 2; p++) {                                              \
        int row = p * 64 + krow, idx = kidx ^ (row & 7);                       \
        async_copy16(K + kqbase + (size_t)((kt_) * 128 + row) * D + idx * 8,   \
                     &Kl[buf_][(p * 512 + wave * 64) * 8]);                    \
    }                                                                          \
    _Pragma("unroll")                                                          \
    for (int p = 0; p < 2; p++) {                                              \
        int row = p * 32 + vrow, idx = vidx ^ (row & 15);                      \
        async_copy16(V + vbase + (size_t)row * 2048 + (kt_) * 128 + idx * 8,   \
                     &Vl[buf_][(p * 512 + wave * 64) * 8]);                    \
    }                                                                          \
} while (0)

    // exp2+pack of one QK acc half-tile into two PV A-frags
#define EXP_PACK(accv, p0_, p1_) do {                                          \
    _Pragma("unroll")                                                          \
    for (int r = 0; r < 8; r++)                                                \
        p0_.hh[r] = (bf16)__builtin_amdgcn_exp2f(accv[r]);                     \
    _Pragma("unroll")                                                          \
    for (int r = 0; r < 8; r++)                                                \
        p1_.hh[r] = (bf16)__builtin_amdgcn_exp2f(accv[8 + r]);                 \
} while (0)

    // PV + denominator for one kg
#define PV_KG(kg_, p0_, p1_) do {                                              \
    __builtin_amdgcn_s_setprio(1);                                             \
    ol = MFMA32_BF16(p0_.s, vones, ol);                                        \
    ol = MFMA32_BF16(p1_.s, vones, ol);                                        \
    _Pragma("unroll")                                                          \
    for (int db = 0; db < 2; db++) {                                           \
        _Pragma("unroll")                                                      \
        for (int c = 0; c < 2; c++) {                                          \
            const int m = (kg_) * 4 + 2 * c;                                   \
            union { bs4 hh[2]; short8 s; } vf;                                 \
            vf.hh[0] = *(const bs4*)&Vlc[vbl + db * 4096 + ((x0 ^ m) * 8)];    \
            vf.hh[1] = *(const bs4*)&Vlc[vbl + db * 4096 + ((x0 ^ (m + 1)) * 8)];\
            if (db == 0) o0 = MFMA32_BF16(c ? p1_.s : p0_.s, vf.s, o0);        \
            else         o1 = MFMA32_BF16(c ? p1_.s : p0_.s, vf.s, o1);        \
        }                                                                      \
    }                                                                          \
    __builtin_amdgcn_s_setprio(0);                                             \
} while (0)

    STAGE_KV(0, 0);                                  // prologue

    for (int kt = 0; kt < S / 128; kt++) {
        const int cur = kt & 1;
        if (kt < S / 128 - 1) {
            STAGE_KV(cur ^ 1, kt + 1);               // issue next tile's loads
            asm volatile("s_waitcnt vmcnt(4)" ::: "memory");  // prev tile done
        } else {
            asm volatile("s_waitcnt vmcnt(0)" ::: "memory");
        }
        __builtin_amdgcn_s_barrier();                // buf[cur] ready for all

        const bf16* Klc = Kl[cur];
        const bf16* Vlc = Vl[cur];

        // ---- kg-pipelined body ----
        const bf16* kb0 = Klc + khbase;
        const bf16* kb1 = Klc + khbase + 32 * 64;

        // QK(0)
        short8 kfa = *(const short8*)(kb0 + koff[0]);
        short8 kfb = *(const short8*)(kb0 + koff[1]);
        short8 kfc = *(const short8*)(kb0 + koff[2]);
        short8 kfd = *(const short8*)(kb0 + koff[3]);
        __builtin_amdgcn_s_setprio(1);
        f32x16 a0;
#pragma unroll
        for (int i = 0; i < 16; i++) a0[i] = 0.f;
        a0 = MFMA32_BF16(kfa, aq[0], a0);            // S^T: m=key, n=query
        a0 = MFMA32_BF16(kfb, aq[1], a0);
        a0 = MFMA32_BF16(kfc, aq[2], a0);
        a0 = MFMA32_BF16(kfd, aq[3], a0);
        __builtin_amdgcn_s_setprio(0);

        // K-frags(1): ds_reads overlap a0's MFMAs
        kfa = *(const short8*)(kb1 + koff[0]);
        kfb = *(const short8*)(kb1 + koff[1]);
        kfc = *(const short8*)(kb1 + koff[2]);
        kfd = *(const short8*)(kb1 + koff[3]);

        // exp2(0) -- first VALU op waits only on a0
        union { bf16 hh[8]; short8 s; } pk00, pk01, pk10, pk11;
        EXP_PACK(a0, pk00, pk01);

        // QK(1) into the matrix pipe
        __builtin_amdgcn_s_setprio(1);
        f32x16 a1;
#pragma unroll
        for (int i = 0; i < 16; i++) a1[i] = 0.f;
        a1 = MFMA32_BF16(kfa, aq[0], a1);
        a1 = MFMA32_BF16(kfb, aq[1], a1);
        a1 = MFMA32_BF16(kfc, aq[2], a1);
        a1 = MFMA32_BF16(kfd, aq[3], a1);
        __builtin_amdgcn_s_setprio(0);

        PV_KG(0, pk00, pk01);                        // PV(0) queues behind QK(1)
        EXP_PACK(a1, pk10, pk11);                    // VALU overlaps PV(0) MFMAs
        PV_KG(1, pk10, pk11);

        asm volatile("" ::: "memory");               // keep ds_reads above
        __builtin_amdgcn_s_barrier();                // all reads done before
                                                     // next iter overwrites
    }
#undef STAGE_KV
#undef EXP_PACK
#undef PV_KG

    // ---- cross-wave (key-half) reduction through the dead K/V buffers.
    // o0/o1 through Kl (8192 floats); ol through Vl (4096 of 8192 floats).
    // reg<->query alignment: o*[r] and ol[r] are the same q = (r&3)+8*(r>>2)
    // +4*hi, so inv is lane-local -- no shuffles. ----
    float* os = (float*)&Kl[0][0];      // 4 waves x 32 regs x 64 lanes = 32 KB
    float* ls = (float*)&Vl[0][0];      // 4 waves x 16 regs x 64 lanes = 16 KB
    if (wave >= 4) {
        const int w4 = wave - 4;
#pragma unroll
        for (int i = 0; i < 16; i++) os[(w4 * 32 + i) * 64 + lane] = o0[i];
#pragma unroll
        for (int i = 0; i < 16; i++) os[(w4 * 32 + 16 + i) * 64 + lane] = o1[i];
#pragma unroll
        for (int i = 0; i < 16; i++) ls[(w4 * 16 + i) * 64 + lane] = ol[i];
    }
    __syncthreads();
    if (wave < 4) {
#pragma unroll
        for (int i = 0; i < 16; i++) o0[i] += os[(wave * 32 + i) * 64 + lane];
#pragma unroll
        for (int i = 0; i < 16; i++) o1[i] += os[(wave * 32 + 16 + i) * 64 + lane];
#pragma unroll
        for (int i = 0; i < 16; i++) ol[i] += ls[(wave * 16 + i) * 64 + lane];
        // output: reg r -> q = (r&3)+8*(r>>2)+4*hi, d = lo / 32+lo;
        // ol[r] is q's denominator (replicated over lo) -> lane-local inv.
#pragma unroll
        for (int r = 0; r < 16; r++) {
            float invr = __builtin_amdgcn_rcpf(ol[r]);
            const int q = (r & 3) + 8 * (r >> 2) + 4 * hi;
            const int row = qt * 128 + qw * 32 + q;
            bf16* op = O + ((size_t)b * S + row) * D + h * 64 + lo;
            op[0]  = (bf16)(o0[r] * invr);
            op[32] = (bf16)(o1[r] * invr);
        }
    }
}

// ---------------------------------------------------------------------------
extern "C" void kernel_launch(void* const* d_in, const int* in_sizes, int n_in,
                              void* d_out, int out_size, void* d_ws, size_t ws_size,
                              hipStream_t stream) {
    (void)in_sizes; (void)n_in; (void)out_size; (void)ws_size;
    const float* q  = (const float*)d_in[0];
    const float* k  = (const float*)d_in[1];
    const float* v  = (const float*)d_in[2];
    const float* Wq = (const float*)d_in[3];
    const float* bq = (const float*)d_in[4];
    const float* Wk = (const float*)d_in[5];
    const float* bk = (const float*)d_in[6];
    const float* Wv = (const float*)d_in[7];
    const float* bv = (const float*)d_in[8];
    const float* Wo = (const float*)d_in[9];
    const float* bo = (const float*)d_in[10];
    float* out = (float*)d_out;

    const int M = 4096, N = 1024;
    const size_t MN = (size_t)M * N;      // 4M elems
    const size_t NN = (size_t)N * N;      // 1M elems
    bf16* qb  = (bf16*)d_ws;
    bf16* kb  = qb + MN;
    bf16* vb  = kb + MN;
    bf16* wqb = vb + MN;
    bf16* wkb = wqb + NN;
    bf16* wvb = wkb + NN;
    bf16* wob = wvb + NN;
    bf16* Qp  = wob + NN;
    bf16* Kp  = Qp + MN;
    bf16* Vt  = Kp + MN;                  // [b][h][64][2048]
    bf16* AO  = qb;                       // qb dead after QKV projection

    dim3 blk(256);
    convert_all<<<4096, blk, 0, stream>>>(q, k, v, Wq, Wk, Wv, Wo,
                                          qb, kb, vb, wqb, wkb, wvb, wob);

    gemm_qkv<<<dim3(32, 24), blk, 0, stream>>>(qb, kb, vb, wqb, wkb, wvb,
                                               bq, bk, bv, Qp, Kp, Vt);

    attn128q<<<dim3(32, 16), dim3(512), 0, stream>>>(Qp, Kp, Vt, AO);

    gemm_fin<<<dim3(32, 16), blk, 0, stream>>>(AO, wob, bo, out);
}

// Round 12
// 210.736 us; speedup vs baseline: 1.0356x; 1.0356x over previous
//
#include <hip/hip_runtime.h>
#include <hip/hip_bf16.h>

typedef __hip_bfloat16 bf16;
typedef short short8 __attribute__((ext_vector_type(8)));
typedef short bs4 __attribute__((ext_vector_type(4)));   // NOT short4 (HIP owns that name)
typedef float f32x4 __attribute__((ext_vector_type(4)));
typedef float f32x16 __attribute__((ext_vector_type(16)));

#define MFMA_BF16(a, b, c) __builtin_amdgcn_mfma_f32_16x16x32_bf16(a, b, c, 0, 0, 0)
#define MFMA32_BF16(a, b, c) __builtin_amdgcn_mfma_f32_32x32x16_bf16(a, b, c, 0, 0, 0)

// log2(e)/sqrt(1024): folded into Q-projection so attn exp is raw v_exp_f32
#define QSCALE 0.045084439f

// async global->LDS 16B: LDS dest is wave-uniform base; HW scatters lane i to +16B*i
__device__ __forceinline__ void async_copy16(const bf16* g, bf16* l) {
    __builtin_amdgcn_global_load_lds(
        (const __attribute__((address_space(1))) unsigned int*)(const void*)g,
        (__attribute__((address_space(3))) unsigned int*)(void*)l, 16, 0, 0);
}

// ---------------------------------------------------------------------------
// f32 -> bf16 pre-convert: q,k,v (4M elems each), Wq,Wk,Wv,Wo (1M each).
// ---------------------------------------------------------------------------
__global__ __launch_bounds__(256) void convert_all(
    const float* __restrict__ q, const float* __restrict__ k, const float* __restrict__ v,
    const float* __restrict__ wq, const float* __restrict__ wk,
    const float* __restrict__ wv, const float* __restrict__ wo,
    bf16* __restrict__ qb, bf16* __restrict__ kb, bf16* __restrict__ vb,
    bf16* __restrict__ wqb, bf16* __restrict__ wkb, bf16* __restrict__ wvb,
    bf16* __restrict__ wob)
{
    int blk = blockIdx.x;
    const float* s; bf16* d; int rel;
    if      (blk < 1024) { s = q;  d = qb;  rel = blk; }
    else if (blk < 2048) { s = k;  d = kb;  rel = blk - 1024; }
    else if (blk < 3072) { s = v;  d = vb;  rel = blk - 2048; }
    else if (blk < 3328) { s = wq; d = wqb; rel = blk - 3072; }
    else if (blk < 3584) { s = wk; d = wkb; rel = blk - 3328; }
    else if (blk < 3840) { s = wv; d = wvb; rel = blk - 3584; }
    else                 { s = wo; d = wob; rel = blk - 3840; }
    size_t base = (size_t)rel * 1024 + threadIdx.x;  // float4 index
#pragma unroll
    for (int i = 0; i < 4; i++) {
        float4 f = ((const float4*)s)[base + i * 256];
        union { bf16 h[4]; uint2 u; } pk;
        pk.h[0] = (bf16)f.x; pk.h[1] = (bf16)f.y;
        pk.h[2] = (bf16)f.z; pk.h[3] = (bf16)f.w;
        ((uint2*)d)[base + i * 256] = pk.u;
    }
}

// ---------------------------------------------------------------------------
// Fused QKV projection: grid (x = m-block [32], y = n-block + 8*sel [24]).
// XCD swizzle: blocks sharing the A-row-tile (fixed x, all y) have
// id = x + 32*y -> id%8 == x%8 -> same XCD -> A fetched once per XCD.
// 128x128 tile, BK=64, global_load_lds staging, XOR chunk swizzle.
// R9 single-barrier T3 loop (kept: measured net positive for the GEMMs).
// sel 0: Q (scaled by QSCALE); sel 1: K; sel 2: V transposed [b][h][64][2048].
// ---------------------------------------------------------------------------
__global__ __launch_bounds__(256) void gemm_qkv(
    const bf16* __restrict__ qb, const bf16* __restrict__ kb, const bf16* __restrict__ vb,
    const bf16* __restrict__ wqb, const bf16* __restrict__ wkb, const bf16* __restrict__ wvb,
    const float* __restrict__ bq, const float* __restrict__ bk, const float* __restrict__ bv,
    bf16* __restrict__ Qp, bf16* __restrict__ Kp, bf16* __restrict__ Vt)
{
    __shared__ bf16 Al[2][128 * 64];   // 2 x 16 KB
    __shared__ bf16 Bl[2][128 * 64];   // 2 x 16 KB

    const int sel = blockIdx.y >> 3;
    const bf16* A; const bf16* W; const float* bias;
    if      (sel == 0) { A = qb; W = wqb; bias = bq; }
    else if (sel == 1) { A = kb; W = wkb; bias = bk; }
    else               { A = vb; W = wvb; bias = bv; }

    const int K = 1024, N = 1024;
    const int t = threadIdx.x;
    const int lane = t & 63, wave = t >> 6;
    const int ln = lane & 15, quad = lane >> 4;
    const int wm = wave >> 1, wn = wave & 1;
    const int m0 = blockIdx.x * 128, n0 = (blockIdx.y & 7) * 128;

    f32x4 acc[4][4];
#pragma unroll
    for (int i = 0; i < 4; i++)
#pragma unroll
        for (int j = 0; j < 4; j++) acc[i][j] = (f32x4){0.f, 0.f, 0.f, 0.f};

    const int lk = ln & 7;
    const int srow = t >> 3, sidx0 = t & 7;

#define STAGE_AB(buf_, k0_) do {                                               \
    const bf16* Ab = A + (size_t)m0 * K + (k0_);                               \
    const bf16* Wb = W + (size_t)n0 * K + (k0_);                               \
    _Pragma("unroll")                                                          \
    for (int p = 0; p < 4; p++) {                                              \
        int row = p * 32 + srow, idx = sidx0 ^ (row & 7);                      \
        async_copy16(Ab + (size_t)row * K + idx * 8,                           \
                     &Al[buf_][(p * 256 + wave * 64) * 8]);                    \
    }                                                                          \
    _Pragma("unroll")                                                          \
    for (int p = 0; p < 4; p++) {                                              \
        int row = p * 32 + srow, idx = sidx0 ^ (row & 7);                      \
        async_copy16(Wb + (size_t)row * K + idx * 8,                           \
                     &Bl[buf_][(p * 256 + wave * 64) * 8]);                    \
    }                                                                          \
} while (0)

    STAGE_AB(0, 0);                                  // prologue
    asm volatile("s_waitcnt vmcnt(0)" ::: "memory");
    __builtin_amdgcn_s_barrier();

    for (int k0 = 0; k0 < K; k0 += 64) {
        const int cur = (k0 >> 6) & 1;
        if (k0 < K - 64)
            STAGE_AB(cur ^ 1, k0 + 64);              // overlaps this compute

        const bf16* Alc = Al[cur];
        const bf16* Blc = Bl[cur];

#pragma unroll
        for (int kk = 0; kk < 2; kk++) {
            short8 af[4], bfr[4];
#pragma unroll
            for (int i = 0; i < 4; i++) {
                int r = wm * 64 + i * 16 + ln;
                af[i] = *(const short8*)&Alc[r * 64 + (((kk << 2) | quad) ^ lk) * 8];
            }
#pragma unroll
            for (int j = 0; j < 4; j++) {
                int r = wn * 64 + j * 16 + ln;
                bfr[j] = *(const short8*)&Blc[r * 64 + (((kk << 2) | quad) ^ lk) * 8];
            }
            __builtin_amdgcn_s_setprio(1);
#pragma unroll
            for (int i = 0; i < 4; i++)
#pragma unroll
                for (int j = 0; j < 4; j++)
                    acc[i][j] = MFMA_BF16(af[i], bfr[j], acc[i][j]);
            __builtin_amdgcn_s_setprio(0);
        }

        asm volatile("s_waitcnt vmcnt(0)" ::: "memory"); // next buf staged
        __builtin_amdgcn_s_barrier();                    // all reads+loads done
    }
#undef STAGE_AB

    // epilogue: col(n) = ln, row(m) = quad*4 + r
#pragma unroll
    for (int j = 0; j < 4; j++) {
        int c = n0 + wn * 64 + j * 16 + ln;
        float bv2 = bias[c];
        if (sel == 2) {
            int h = c >> 6, dd = c & 63;
#pragma unroll
            for (int i = 0; i < 4; i++) {
                int m = m0 + wm * 64 + i * 16 + quad * 4;
                int bb = m >> 11, s = m & 2047;
                union { bf16 h4[4]; uint2 u; } pk;
#pragma unroll
                for (int r = 0; r < 4; r++) pk.h4[r] = (bf16)(acc[i][j][r] + bv2);
                *(uint2*)&Vt[(((size_t)(bb * 16 + h)) * 64 + dd) * 2048 + s] = pk.u;
            }
        } else {
            bf16* out = (sel == 0) ? Qp : Kp;
            float scl = (sel == 0) ? QSCALE : 1.0f;
#pragma unroll
            for (int i = 0; i < 4; i++) {
                int rb = m0 + wm * 64 + i * 16 + quad * 4;
#pragma unroll
                for (int r = 0; r < 4; r++)
                    out[(size_t)(rb + r) * N + c] = (bf16)((acc[i][j][r] + bv2) * scl);
            }
        }
    }
}

// ---------------------------------------------------------------------------
// Final GEMM: out = AO * Wo^T + bo, f32 output. 128(M)x64(N) tile, dbuf,
// single-barrier T3 loop, grid (32,16). (R9 form, kept.)
// ---------------------------------------------------------------------------
__global__ __launch_bounds__(256) void gemm_fin(
    const bf16* __restrict__ A, const bf16* __restrict__ W,
    const float* __restrict__ bias, float* __restrict__ C)
{
    __shared__ bf16 Al[2][128 * 64];   // 32 KB
    __shared__ bf16 Bl[2][64 * 64];    // 16 KB

    const int K = 1024, N = 1024;
    const int t = threadIdx.x;
    const int lane = t & 63, wave = t >> 6;
    const int ln = lane & 15, quad = lane >> 4;
    const int wm = wave >> 1, wn = wave & 1;
    const int m0 = blockIdx.x * 128, n0 = blockIdx.y * 64;

    f32x4 acc[4][2];
#pragma unroll
    for (int i = 0; i < 4; i++)
#pragma unroll
        for (int j = 0; j < 2; j++) acc[i][j] = (f32x4){0.f, 0.f, 0.f, 0.f};

    const int lk = ln & 7;
    const int srow = t >> 3, sidx0 = t & 7;

#define STAGE_AB(buf_, k0_) do {                                               \
    const bf16* Ab = A + (size_t)m0 * K + (k0_);                               \
    const bf16* Wb = W + (size_t)n0 * K + (k0_);                               \
    _Pragma("unroll")                                                          \
    for (int p = 0; p < 4; p++) {                                              \
        int row = p * 32 + srow, idx = sidx0 ^ (row & 7);                      \
        async_copy16(Ab + (size_t)row * K + idx * 8,                           \
                     &Al[buf_][(p * 256 + wave * 64) * 8]);                    \
    }                                                                          \
    _Pragma("unroll")                                                          \
    for (int p = 0; p < 2; p++) {                                              \
        int row = p * 32 + srow, idx = sidx0 ^ (row & 7);                      \
        async_copy16(Wb + (size_t)row * K + idx * 8,                           \
                     &Bl[buf_][(p * 256 + wave * 64) * 8]);                    \
    }                                                                          \
} while (0)

    STAGE_AB(0, 0);                                  // prologue
    asm volatile("s_waitcnt vmcnt(0)" ::: "memory");
    __builtin_amdgcn_s_barrier();

    for (int k0 = 0; k0 < K; k0 += 64) {
        const int cur = (k0 >> 6) & 1;
        if (k0 < K - 64)
            STAGE_AB(cur ^ 1, k0 + 64);              // overlaps this compute

        const bf16* Alc = Al[cur];
        const bf16* Blc = Bl[cur];

#pragma unroll
        for (int kk = 0; kk < 2; kk++) {
            short8 af[4], bfr[2];
#pragma unroll
            for (int i = 0; i < 4; i++) {
                int r = wm * 64 + i * 16 + ln;
                af[i] = *(const short8*)&Alc[r * 64 + (((kk << 2) | quad) ^ lk) * 8];
            }
#pragma unroll
            for (int j = 0; j < 2; j++) {
                int r = wn * 32 + j * 16 + ln;
                bfr[j] = *(const short8*)&Blc[r * 64 + (((kk << 2) | quad) ^ lk) * 8];
            }
            __builtin_amdgcn_s_setprio(1);
#pragma unroll
            for (int i = 0; i < 4; i++)
#pragma unroll
                for (int j = 0; j < 2; j++)
                    acc[i][j] = MFMA_BF16(af[i], bfr[j], acc[i][j]);
            __builtin_amdgcn_s_setprio(0);
        }

        asm volatile("s_waitcnt vmcnt(0)" ::: "memory");
        __builtin_amdgcn_s_barrier();
    }
#undef STAGE_AB

#pragma unroll
    for (int j = 0; j < 2; j++) {
        int c = n0 + wn * 32 + j * 16 + ln;
        float bv2 = bias[c];
#pragma unroll
        for (int i = 0; i < 4; i++) {
            int rb = m0 + wm * 64 + i * 16 + quad * 4;
#pragma unroll
            for (int r = 0; r < 4; r++)
                C[(size_t)(rb + r) * N + c] = acc[i][j][r] + bv2;
        }
    }
}

// ---------------------------------------------------------------------------
// Flash attention, 32x32x16 MFMA formulation -- EXACT R8 form (measured
// session-best 46.2 us). Grid (x = h + 16*b [32], y = qt [16]), 512
// threads / 8 waves; wave = 32 queries (qw) x key-half (keyhalf).
// Two-barrier loop with counted vmcnt(4) (measured faster than the
// single-barrier variant: 46.2 vs 47.4). Non-pipelined kg body: R11's kg
// software pipeline spilled to scratch (+19.7 MB HBM traffic, 55.6 us) --
// the register wall bites before ILP scheduling pays. R7: ones-MFMA
// denominator (reg<->query map identical to o0/o1; inv lane-local).
// R6/R8: occupancy register-walled at 4 waves/SIMD; matrix floor ~17 us.
// ---------------------------------------------------------------------------
__global__ __launch_bounds__(512, 4) void attn128q(
    const bf16* __restrict__ Q, const bf16* __restrict__ K,
    const bf16* __restrict__ V, bf16* __restrict__ O)
{
    const int S = 2048, D = 1024;
    __shared__ bf16 Kl[2][128 * 64];    // 2 x 16 KB [key][d], 16B-chunk ^(row&7)
    __shared__ bf16 Vl[2][64 * 128];    // 2 x 16 KB [d][key], 16B-chunk ^(row&15)

    const int t = threadIdx.x, lane = t & 63, wave = t >> 6;   // wave 0..7
    const int lo = lane & 31, hi = lane >> 5;
    const int keyhalf = wave >> 2;      // 0: keys 0-63 of tile, 1: keys 64-127
    const int qw = wave & 3;            // query group: q0 = qt*128 + qw*32
    const int h = blockIdx.x & 15, b = blockIdx.x >> 4, qt = blockIdx.y;
    const size_t kqbase = (size_t)b * S * D + (size_t)h * 64;
    const size_t vbase = ((size_t)(b * 16 + h)) * 64 * 2048;

    // Q fragments (pre-scaled by QSCALE): lane: row q0+lo, d = s*16 + hi*8
    const int q0 = qt * 128 + qw * 32;
    short8 aq[4];
    {
        const bf16* qp = Q + kqbase + (size_t)(q0 + lo) * D + hi * 8;
#pragma unroll
        for (int s = 0; s < 4; s++) aq[s] = *(const short8*)(qp + s * 16);
    }
    // Force the Q-load vmcnt wait here, before the pipelined loop.
    asm volatile("" :: "v"(aq[0]), "v"(aq[1]), "v"(aq[2]), "v"(aq[3]));

    f32x16 o0, o1, ol;                   // O accum: d = lo (o0), 32+lo (o1);
                                         // ol = P row-sums (denominator)
#pragma unroll
    for (int i = 0; i < 16; i++) { o0[i] = 0.f; o1[i] = 0.f; ol[i] = 0.f; }

    // ones B-frag (bf16 1.0 splat) for the denominator MFMA
    const short8 vones = (short8)(short)0x3F80;

    // K A-frag offsets: row = keyhalf*64 + kg*32 + lo; row&7 == lo&7, so the
    // swizzled chunk (2s+hi)^(lo&7) is kg-invariant. Element offsets:
    int koff[4];
#pragma unroll
    for (int s = 0; s < 4; s++)
        koff[s] = lo * 64 + (((2 * s + hi) ^ (lo & 7)) * 8);
    const int khbase = keyhalf * 64 * 64;       // elements to this wave's keys

    // V B-frag: element off = (db*32+lo)*128 + ((x0 ^ m)*8) + hi*4,
    // m = kg*4 + 2c + g  (bits 0-2; keyhalf*8 is bit 3 -> XOR-combinable)
    const int x0 = (keyhalf * 8) ^ (lo & 15);
    const int vbl = lo * 128 + hi * 4;

    // staging indices (512 threads: 2 K chunks + 2 V chunks per thread)
    const int krow = t >> 3, kidx = t & 7;        // K: 8 chunks/row
    const int vrow = t >> 4, vidx = t & 15;       // V: 16 chunks/row

#define STAGE_KV(buf_, kt_) do {                                               \
    _Pragma("unroll")                                                          \
    for (int p = 0; p < 2; p++) {                                              \
        int row = p * 64 + krow, idx = kidx ^ (row & 7);                       \
        async_copy16(K + kqbase + (size_t)((kt_) * 128 + row) * D + idx * 8,   \
                     &Kl[buf_][(p * 512 + wave * 64) * 8]);                    \
    }                                                                          \
    _Pragma("unroll")                                                          \
    for (int p = 0; p < 2; p++) {                                              \
        int row = p * 32 + vrow, idx = vidx ^ (row & 15);                      \
        async_copy16(V + vbase + (size_t)row * 2048 + (kt_) * 128 + idx * 8,   \
                     &Vl[buf_][(p * 512 + wave * 64) * 8]);                    \
    }                                                                          \
} while (0)

    STAGE_KV(0, 0);                                  // prologue

    for (int kt = 0; kt < S / 128; kt++) {
        const int cur = kt & 1;
        if (kt < S / 128 - 1) {
            STAGE_KV(cur ^ 1, kt + 1);               // issue next tile's loads
            asm volatile("s_waitcnt vmcnt(4)" ::: "memory");  // prev tile done
        } else {
            asm volatile("s_waitcnt vmcnt(0)" ::: "memory");
        }
        __builtin_amdgcn_s_barrier();                // buf[cur] ready for all

        const bf16* Klc = Kl[cur];
        const bf16* Vlc = Vl[cur];

#pragma unroll
        for (int kg = 0; kg < 2; kg++) {             // 32-key groups
            const bf16* kb = Klc + khbase + kg * (32 * 64);
            short8 kf0 = *(const short8*)(kb + koff[0]);
            short8 kf1 = *(const short8*)(kb + koff[1]);
            short8 kf2 = *(const short8*)(kb + koff[2]);
            short8 kf3 = *(const short8*)(kb + koff[3]);

            __builtin_amdgcn_s_setprio(1);
            f32x16 acc;
#pragma unroll
            for (int i = 0; i < 16; i++) acc[i] = 0.f;
            acc = MFMA32_BF16(kf0, aq[0], acc);      // S^T: m=key, n=query
            acc = MFMA32_BF16(kf1, aq[1], acc);
            acc = MFMA32_BF16(kf2, aq[2], acc);
            acc = MFMA32_BF16(kf3, aq[3], acc);
            __builtin_amdgcn_s_setprio(0);

            // exp2 + pack: PV A-frag chunk c = regs 8c..8c+7 in natural order
            union { bf16 hh[8]; short8 s; } pk0, pk1;
#pragma unroll
            for (int r = 0; r < 8; r++)
                pk0.hh[r] = (bf16)__builtin_amdgcn_exp2f(acc[r]);
#pragma unroll
            for (int r = 0; r < 8; r++)
                pk1.hh[r] = (bf16)__builtin_amdgcn_exp2f(acc[8 + r]);

            // PV: O[q][d] += P'[q][j] V'[j][d], V read at permuted key cols;
            // denominator rides the matrix pipe: ol += P' * ones.
            __builtin_amdgcn_s_setprio(1);
            ol = MFMA32_BF16(pk0.s, vones, ol);
            ol = MFMA32_BF16(pk1.s, vones, ol);
#pragma unroll
            for (int db = 0; db < 2; db++) {
#pragma unroll
                for (int c = 0; c < 2; c++) {
                    const int m = kg * 4 + 2 * c;
                    union { bs4 hh[2]; short8 s; } vf;
                    vf.hh[0] = *(const bs4*)&Vlc[vbl + db * 4096 + ((x0 ^ m) * 8)];
                    vf.hh[1] = *(const bs4*)&Vlc[vbl + db * 4096 + ((x0 ^ (m + 1)) * 8)];
                    if (db == 0) o0 = MFMA32_BF16(c ? pk1.s : pk0.s, vf.s, o0);
                    else         o1 = MFMA32_BF16(c ? pk1.s : pk0.s, vf.s, o1);
                }
            }
            __builtin_amdgcn_s_setprio(0);
        }

        asm volatile("" ::: "memory");               // keep ds_reads above
        __builtin_amdgcn_s_barrier();                // all reads done before
                                                     // next iter overwrites
    }
#undef STAGE_KV

    // ---- cross-wave (key-half) reduction through the dead K/V buffers.
    // o0/o1 through Kl (8192 floats); ol through Vl (4096 of 8192 floats).
    // reg<->query alignment: o*[r] and ol[r] are the same q = (r&3)+8*(r>>2)
    // +4*hi, so inv is lane-local -- no shuffles. ----
    float* os = (float*)&Kl[0][0];      // 4 waves x 32 regs x 64 lanes = 32 KB
    float* ls = (float*)&Vl[0][0];      // 4 waves x 16 regs x 64 lanes = 16 KB
    if (wave >= 4) {
        const int w4 = wave - 4;
#pragma unroll
        for (int i = 0; i < 16; i++) os[(w4 * 32 + i) * 64 + lane] = o0[i];
#pragma unroll
        for (int i = 0; i < 16; i++) os[(w4 * 32 + 16 + i) * 64 + lane] = o1[i];
#pragma unroll
        for (int i = 0; i < 16; i++) ls[(w4 * 16 + i) * 64 + lane] = ol[i];
    }
    __syncthreads();
    if (wave < 4) {
#pragma unroll
        for (int i = 0; i < 16; i++) o0[i] += os[(wave * 32 + i) * 64 + lane];
#pragma unroll
        for (int i = 0; i < 16; i++) o1[i] += os[(wave * 32 + 16 + i) * 64 + lane];
#pragma unroll
        for (int i = 0; i < 16; i++) ol[i] += ls[(wave * 16 + i) * 64 + lane];
        // output: reg r -> q = (r&3)+8*(r>>2)+4*hi, d = lo / 32+lo;
        // ol[r] is q's denominator (replicated over lo) -> lane-local inv.
#pragma unroll
        for (int r = 0; r < 16; r++) {
            float invr = __builtin_amdgcn_rcpf(ol[r]);
            const int q = (r & 3) + 8 * (r >> 2) + 4 * hi;
            const int row = qt * 128 + qw * 32 + q;
            bf16* op = O + ((size_t)b * S + row) * D + h * 64 + lo;
            op[0]  = (bf16)(o0[r] * invr);
            op[32] = (bf16)(o1[r] * invr);
        }
    }
}

// ---------------------------------------------------------------------------
extern "C" void kernel_launch(void* const* d_in, const int* in_sizes, int n_in,
                              void* d_out, int out_size, void* d_ws, size_t ws_size,
                              hipStream_t stream) {
    (void)in_sizes; (void)n_in; (void)out_size; (void)ws_size;
    const float* q  = (const float*)d_in[0];
    const float* k  = (const float*)d_in[1];
    const float* v  = (const float*)d_in[2];
    const float* Wq = (const float*)d_in[3];
    const float* bq = (const float*)d_in[4];
    const float* Wk = (const float*)d_in[5];
    const float* bk = (const float*)d_in[6];
    const float* Wv = (const float*)d_in[7];
    const float* bv = (const float*)d_in[8];
    const float* Wo = (const float*)d_in[9];
    const float* bo = (const float*)d_in[10];
    float* out = (float*)d_out;

    const int M = 4096, N = 1024;
    const size_t MN = (size_t)M * N;      // 4M elems
    const size_t NN = (size_t)N * N;      // 1M elems
    bf16* qb  = (bf16*)d_ws;
    bf16* kb  = qb + MN;
    bf16* vb  = kb + MN;
    bf16* wqb = vb + MN;
    bf16* wkb = wqb + NN;
    bf16* wvb = wkb + NN;
    bf16* wob = wvb + NN;
    bf16* Qp  = wob + NN;
    bf16* Kp  = Qp + MN;
    bf16* Vt  = Kp + MN;                  // [b][h][64][2048]
    bf16* AO  = qb;                       // qb dead after QKV projection

    dim3 blk(256);
    convert_all<<<4096, blk, 0, stream>>>(q, k, v, Wq, Wk, Wv, Wo,
                                          qb, kb, vb, wqb, wkb, wvb, wob);

    gemm_qkv<<<dim3(32, 24), blk, 0, stream>>>(qb, kb, vb, wqb, wkb, wvb,
                                               bq, bk, bv, Qp, Kp, Vt);

    attn128q<<<dim3(32, 16), dim3(512), 0, stream>>>(Qp, Kp, Vt, AO);

    gemm_fin<<<dim3(32, 16), blk, 0, stream>>>(AO, wob, bo, out);
}